// Round 5
// baseline (735.830 us; speedup 1.0000x reference)
//
#include <hip/hip_runtime.h>

#define HID 128
#define NTY 8

typedef __attribute__((ext_vector_type(8))) short bf16x8;
typedef __attribute__((ext_vector_type(4))) float f32x4;

__device__ __forceinline__ unsigned short f2bf(float x) {
    unsigned u = __float_as_uint(x);
    u += 0x7FFF + ((u >> 16) & 1);          // RNE
    return (unsigned short)(u >> 16);
}
__device__ __forceinline__ float bf2f(unsigned short s) {
    return __uint_as_float(((unsigned)s) << 16);
}
__device__ __forceinline__ float sigmoidf_fast(float x) {
    return 1.f / (1.f + __expf(-x));
}
__device__ __forceinline__ float tanhf_fast(float x) {
    return 1.f - 2.f / (1.f + __expf(2.f * x));
}
__device__ __forceinline__ unsigned cvt_pk_bf16(float lo, float hi) {
    unsigned r;
    asm("v_cvt_pk_bf16_f32 %0, %1, %2" : "=v"(r) : "v"(lo), "v"(hi));
    return r;
}

// ---------------- fused prep: h->bf16, W->wfr frags, GRU->wpkf frags, memset-equivalents ----------------
// wfr[(((t*4+kc)*8+cb)*64 + lane)*8 + e] = bf16(W[t][k][d]), d=cb*16+(lane&15), k=kc*32+(lane>>4)*8+e
// wpkf[((kc*24+g3*8+ct)*64 + lane)*8 + e]: kc<4 -> wih, kc>=4 -> whh; d=ct*16+(lane&15), kk=(lane>>4)*8+e
__global__ void conv_all_kernel(const float* __restrict__ h, unsigned short* __restrict__ hbf, int nh,
                                const float* __restrict__ W, unsigned short* __restrict__ wfr,
                                const float* __restrict__ wih, const float* __restrict__ whh,
                                unsigned short* __restrict__ wpkf,
                                int* __restrict__ sortedT, int capE,
                                int* __restrict__ deg, int N, int* __restrict__ tcnt)
{
    int i = blockIdx.x * 256 + threadIdx.x;
    if (i < nh) { hbf[i] = f2bf(h[i]); return; }
    i -= nh;
    if (i < 131072) {
        int e = i & 7, lane = (i >> 3) & 63, cb = (i >> 9) & 7, kc = (i >> 12) & 3, t = i >> 14;
        int lr = lane & 15, quad = lane >> 4;
        int d = cb * 16 + lr;
        int k = kc * 32 + quad * 8 + e;
        wfr[i] = f2bf(W[(t << 14) + (k << 7) + d]);
        return;
    }
    i -= 131072;
    if (i < 98304) {
        int e = i & 7, lane = (i >> 3) & 63, f = i >> 9;   // f = kc*24+g3*8+ct
        int ct = f & 7, fg = f >> 3;                       // fg = kc*3+g3
        int g3 = fg % 3, kc = fg / 3;
        int lr = lane & 15, quad = lane >> 4;
        int d = ct * 16 + lr;
        int kk = quad * 8 + e;
        float v;
        if (kc < 4) v = wih[(g3 * 128 + d) * 128 + kc * 32 + kk];
        else        v = whh[(g3 * 128 + d) * 128 + (kc - 4) * 32 + kk];
        wpkf[i] = f2bf(v);
        return;
    }
    i -= 98304;
    if (i < capE) { sortedT[i] = -1; return; }
    i -= capE;
    if (i < N) { deg[i] = 0; return; }
    i -= N;
    if (i < NTY) tcnt[i] = 0;
}

// ---------------- sort bookkeeping (R0-proven) ----------------
__global__ void hist_kernel(const int* __restrict__ etype, const int* __restrict__ ei,
                            int E, int* __restrict__ tcnt, int* __restrict__ deg) {
    __shared__ int lc[NTY];
    if (threadIdx.x < NTY) lc[threadIdx.x] = 0;
    __syncthreads();
    int stride = gridDim.x * blockDim.x;
    for (int i = blockIdx.x * blockDim.x + threadIdx.x; i < E; i += stride) {
        atomicAdd(&lc[etype[i]], 1);
        if (deg) atomicAdd(&deg[ei[E + i]], 1);
    }
    __syncthreads();
    if (threadIdx.x < NTY) atomicAdd(&tcnt[threadIdx.x], lc[threadIdx.x]);
}

__global__ void scanA_kernel(const int* __restrict__ deg, int* __restrict__ start,
                             int* __restrict__ bsum, int N) {
    __shared__ int s[256];
    int i = blockIdx.x * 256 + threadIdx.x;
    int v = (i < N) ? deg[i] : 0;
    s[threadIdx.x] = v;
    __syncthreads();
    for (int off = 1; off < 256; off <<= 1) {
        int t = (threadIdx.x >= off) ? s[threadIdx.x - off] : 0;
        __syncthreads();
        s[threadIdx.x] += t;
        __syncthreads();
    }
    if (i < N) start[i] = s[threadIdx.x] - v;
    if (threadIdx.x == 255) bsum[blockIdx.x] = s[255];
}

// block-sum scan + fused 8-bin type scan (padded to 128)
__global__ void scanB_kernel(int* __restrict__ bsum, int nb,
                             const int* __restrict__ tcnt, int* __restrict__ tcur) {
    __shared__ int s[512];
    int tx = threadIdx.x;
    int v = (tx < nb) ? bsum[tx] : 0;
    s[tx] = v;
    __syncthreads();
    for (int off = 1; off < 512; off <<= 1) {
        int t = (tx >= off) ? s[tx - off] : 0;
        __syncthreads();
        s[tx] += t;
        __syncthreads();
    }
    if (tx < nb) bsum[tx] = s[tx] - v;
    if (tx == 0) {
        int off = 0;
        for (int t = 0; t < NTY; ++t) { tcur[t] = off; off += (tcnt[t] + 127) & ~127; }
    }
}

__global__ void scanC_kernel(int* __restrict__ start, const int* __restrict__ bsum,
                             int* __restrict__ dcur, int N, int E) {
    int i = blockIdx.x * 256 + threadIdx.x;
    if (i < N) {
        int v = start[i] + bsum[blockIdx.x];
        start[i] = v;
        dcur[i] = v;
    }
    if (i == 0) start[N] = E;
}

// block-aggregated scatter: 8 global tcur atomics per BLOCK (R0-proven)
__global__ __launch_bounds__(256) void scatter_agg(
    const int* __restrict__ etype, const int* __restrict__ ei, int E,
    int* __restrict__ tcur, int* __restrict__ dcur,
    int* __restrict__ sortedT, int* __restrict__ q, int mode)
{
    __shared__ int lcnt[NTY];
    __shared__ int lbase[NTY];
    int tx = threadIdx.x;
    int chunk = (E + gridDim.x - 1) / gridDim.x;
    int s = blockIdx.x * chunk;
    int e = s + chunk; if (e > E) e = E;
    if (tx < NTY) lcnt[tx] = 0;
    __syncthreads();
    for (int i = s + tx; i < e; i += 256)
        atomicAdd(&lcnt[etype[i]], 1);
    __syncthreads();
    if (tx < NTY) {
        lbase[tx] = atomicAdd(&tcur[tx], lcnt[tx]);
        lcnt[tx] = 0;
    }
    __syncthreads();
    for (int i = s + tx; i < e; i += 256) {
        int t = etype[i];
        int lp = atomicAdd(&lcnt[t], 1);
        sortedT[lbase[t] + lp] = i;
        if (mode) q[i] = atomicAdd(&dcur[ei[E + i]], 1);
    }
}

// ---------------- msg GEMM: 128-edge x 128-d tile, W direct from L2 (no K-loop barriers) ----------------
// Operand-swapped MFMA: D[d][e]; lane holds 4 consecutive d -> packed 8B stores.
__global__ __launch_bounds__(256) void msg_gemm(
    const unsigned short* __restrict__ hbf, const int* __restrict__ ei, int E,
    const int* __restrict__ etype, const unsigned short* __restrict__ wfr,
    const float* __restrict__ bias, const int* __restrict__ sortedT,
    const int* __restrict__ q, unsigned short* __restrict__ M,
    float* __restrict__ msum, int mode)
{
    __shared__ unsigned short hs[128][136];
    __shared__ int srcs[128], aux[128];
    __shared__ int stype;

    int tx = threadIdx.x;
    int base = blockIdx.x * 128;
    if (tx < 128) {
        int id = sortedT[base + tx];
        srcs[tx] = (id >= 0) ? ei[id] : -1;
        aux[tx]  = (id >= 0) ? (mode ? ei[E + id] : q[id]) : -1;
    }
    if (tx == 0) { int id0 = sortedT[base]; stype = (id0 >= 0) ? etype[id0] : -1; }
    __syncthreads();
    int t = stype;
    if (t < 0) return;

    for (int f = tx; f < 2048; f += 256) {
        int row = f >> 4, c8 = (f & 15) * 8;
        int s = srcs[row]; if (s < 0) s = 0;
        *(uint4*)&hs[row][c8] = *(const uint4*)&hbf[(size_t)s * 128 + c8];
    }
    __syncthreads();

    int lane = tx & 63, w = tx >> 6;
    int r0 = (w >> 1) * 64, c0 = (w & 1) * 64;   // r0: edge-tile base, c0: d-tile base
    int lr = lane & 15, quad = lane >> 4;
    f32x4 acc[4][4] = {};   // [rb(e-tile)][cb(d-tile)], D[d][e] per tile

    // W fragments lane-coalesced from L2: value-identical to R0's Bs fragments.
    const unsigned short* wt = wfr + (t << 14) + ((unsigned)(c0 >> 4) << 9) + (lane << 3);
    #pragma unroll
    for (int kc = 0; kc < 4; ++kc) {
        bf16x8 af[4], wf[4];
        #pragma unroll
        for (int rb = 0; rb < 4; ++rb) af[rb] = *(const bf16x8*)&hs[r0 + rb * 16 + lr][kc * 32 + quad * 8];
        #pragma unroll
        for (int cb = 0; cb < 4; ++cb) wf[cb] = *(const bf16x8*)&wt[(kc << 12) + (cb << 9)];
        #pragma unroll
        for (int rb = 0; rb < 4; ++rb)
            #pragma unroll
            for (int cb = 0; cb < 4; ++cb)
                acc[rb][cb] = __builtin_amdgcn_mfma_f32_16x16x32_bf16(wf[cb], af[rb], acc[rb][cb], 0, 0, 0);
    }

    // epilogue: e = r0+rb*16+lr, d = c0+cb*16+quad*4+reg (4 consecutive)
    float4 bv4[4];
    #pragma unroll
    for (int cb = 0; cb < 4; ++cb)
        bv4[cb] = *(const float4*)&bias[t * 128 + c0 + cb * 16 + quad * 4];

    #pragma unroll
    for (int rb = 0; rb < 4; ++rb) {
        int e = r0 + rb * 16 + lr;
        int mr = aux[e];
        if (mr < 0) continue;
        #pragma unroll
        for (int cb = 0; cb < 4; ++cb) {
            int d0 = c0 + cb * 16 + quad * 4;
            f32x4 a = acc[rb][cb];
            if (mode) {
                atomicAdd(&msum[(size_t)mr * 128 + d0 + 0], a[0] + bv4[cb].x);
                atomicAdd(&msum[(size_t)mr * 128 + d0 + 1], a[1] + bv4[cb].y);
                atomicAdd(&msum[(size_t)mr * 128 + d0 + 2], a[2] + bv4[cb].z);
                atomicAdd(&msum[(size_t)mr * 128 + d0 + 3], a[3] + bv4[cb].w);
            } else {
                uint2 v;
                v.x = (unsigned)f2bf(a[0] + bv4[cb].x) | ((unsigned)f2bf(a[1] + bv4[cb].y) << 16);
                v.y = (unsigned)f2bf(a[2] + bv4[cb].z) | ((unsigned)f2bf(a[3] + bv4[cb].w) << 16);
                *(uint2*)&M[(size_t)mr * 128 + d0] = v;
            }
        }
    }
}

// ---------------- fused seg-reduce + GRU: 64 nodes/block ----------------
// Stage A v2: edge-parallel streaming over each wave's contiguous M-row range,
// LDS f32 atomic accumulation (no per-lane serial latency chain).
// GRU: sequential gates + d-half split reading macc f32 directly (cvt_pk on the fly).
__global__ __launch_bounds__(256) void gru_fused(
    const unsigned short* __restrict__ M, const int* __restrict__ start,
    const float* __restrict__ msum_fb, const unsigned short* __restrict__ hbf,
    const unsigned short* __restrict__ wpkf, const float* __restrict__ bih,
    const float* __restrict__ bhh, const float* __restrict__ hf,
    float* __restrict__ out, int N, int mode)
{
    __shared__ __align__(16) float macc[64][132];   // stride 132: 16B-aligned rows, bank rotation node*4
    __shared__ int bnds_l[65];

    int tx = threadIdx.x;
    int n0 = blockIdx.x * 64;
    int lane = tx & 63, w = tx >> 6;
    int lr = lane & 15, quad = lane >> 4;

    // zero macc (vectorized) + stage segment bounds
    for (int i = tx; i < 64 * 132 / 4; i += 256)
        ((f32x4*)macc)[i] = f32x4{0.f, 0.f, 0.f, 0.f};
    if (mode == 0 && tx <= 64) {
        int idx = n0 + tx; if (idx > N) idx = N;
        bnds_l[tx] = start[idx];
    }
    __syncthreads();

    if (mode == 0) {
        // wave w streams rows of its own 16 nodes: [bnds_l[w*16], bnds_l[w*16+16])
        int row_off = quad;        // 4 rows per iteration
        int c = lr;                // 16 chunks of 16B per 256B row
        int lo = bnds_l[w * 16], hi = bnds_l[w * 16 + 16];
        int cur = w * 16;
        int nxt = bnds_l[cur + 1];
        int r = lo + row_off;
        uint4 v = {};
        if (r < hi) v = *(const uint4*)&M[(size_t)r * 128 + c * 8];
        while (r < hi) {
            int rn = r + 4;
            uint4 vn = {};
            if (rn < hi) vn = *(const uint4*)&M[(size_t)rn * 128 + c * 8];
            while (r >= nxt) { ++cur; nxt = bnds_l[cur + 1]; }
            const unsigned short* pv = (const unsigned short*)&v;
            float* mrow = &macc[cur][c * 8];
            #pragma unroll
            for (int j = 0; j < 8; ++j) atomicAdd(&mrow[j], bf2f(pv[j]));
            v = vn; r = rn;
        }
    } else {
        for (int i = tx; i < 2048; i += 256) {
            int node = i >> 5, q4 = (i & 31) * 4;
            int n = n0 + node; int nc2 = (n < N) ? n : N - 1;
            *(f32x4*)&macc[node][q4] = *(const f32x4*)&msum_fb[(size_t)nc2 * 128 + q4];
        }
    }
    __syncthreads();

    // ---- GRU phase ----
    int node = n0 + w * 16 + lr;
    int mrow_i = w * 16 + lr;
    bool valid = node < N;
    int nc = valid ? node : (N - 1);

    bf16x8 afh[4];   // h fragments, cached
    {
        const unsigned short* hrow = hbf + ((size_t)nc << 7) + (quad << 3);
        #pragma unroll
        for (int k4 = 0; k4 < 4; ++k4) afh[k4] = *(const bf16x8*)&hrow[k4 * 32];
    }
    const unsigned short* wg = wpkf + (lane << 3);

    #pragma unroll
    for (int dh = 0; dh < 2; ++dh) {
        f32x4 aR[4] = {}, aZ[4] = {}, aH[4] = {};
        #pragma unroll
        for (int kc = 0; kc < 8; ++kc) {
            bf16x8 af;
            if (kc < 4) {
                const float* mp = &macc[mrow_i][kc * 32 + quad * 8];
                f32x4 L = *(const f32x4*)mp, H = *(const f32x4*)(mp + 4);
                int4 au;
                au.x = (int)cvt_pk_bf16(L[0], L[1]);
                au.y = (int)cvt_pk_bf16(L[2], L[3]);
                au.z = (int)cvt_pk_bf16(H[0], H[1]);
                au.w = (int)cvt_pk_bf16(H[2], H[3]);
                af = *(const bf16x8*)&au;
            } else {
                af = afh[kc - 4];
            }
            #pragma unroll
            for (int cg = 0; cg < 4; ++cg) {
                int ct = dh * 4 + cg;
                bf16x8 wfR = *(const bf16x8*)&wg[(unsigned)((kc * 3 + 0) * 8 + ct) << 9];
                aR[cg] = __builtin_amdgcn_mfma_f32_16x16x32_bf16(wfR, af, aR[cg], 0, 0, 0);
                bf16x8 wfZ = *(const bf16x8*)&wg[(unsigned)((kc * 3 + 1) * 8 + ct) << 9];
                aZ[cg] = __builtin_amdgcn_mfma_f32_16x16x32_bf16(wfZ, af, aZ[cg], 0, 0, 0);
                if (kc >= 4) {
                    bf16x8 wfH = *(const bf16x8*)&wg[(unsigned)((kc * 3 + 2) * 8 + ct) << 9];
                    aH[cg] = __builtin_amdgcn_mfma_f32_16x16x32_bf16(wfH, af, aH[cg], 0, 0, 0);
                }
            }
        }
        // r, z; fold n's h-part:  aH = bin + r*(aH + bhn)
        f32x4 rv[4], zv[4];
        #pragma unroll
        for (int cg = 0; cg < 4; ++cg) {
            int d0 = (dh * 4 + cg) * 16 + quad * 4;
            f32x4 bir = *(const f32x4*)&bih[d0],       bhr = *(const f32x4*)&bhh[d0];
            f32x4 biz = *(const f32x4*)&bih[128 + d0], bhz = *(const f32x4*)&bhh[128 + d0];
            f32x4 bin = *(const f32x4*)&bih[256 + d0], bhn = *(const f32x4*)&bhh[256 + d0];
            #pragma unroll
            for (int j = 0; j < 4; ++j) {
                rv[cg][j] = sigmoidf_fast(aR[cg][j] + bir[j] + bhr[j]);
                zv[cg][j] = sigmoidf_fast(aZ[cg][j] + biz[j] + bhz[j]);
                aH[cg][j] = bin[j] + rv[cg][j] * (aH[cg][j] + bhn[j]);
            }
        }
        // n's m-part accumulates onto folded value via MFMA C-operand
        #pragma unroll
        for (int kc = 0; kc < 4; ++kc) {
            const float* mp = &macc[mrow_i][kc * 32 + quad * 8];
            f32x4 L = *(const f32x4*)mp, H = *(const f32x4*)(mp + 4);
            int4 au;
            au.x = (int)cvt_pk_bf16(L[0], L[1]);
            au.y = (int)cvt_pk_bf16(L[2], L[3]);
            au.z = (int)cvt_pk_bf16(H[0], H[1]);
            au.w = (int)cvt_pk_bf16(H[2], H[3]);
            bf16x8 af = *(const bf16x8*)&au;
            #pragma unroll
            for (int cg = 0; cg < 4; ++cg) {
                bf16x8 wfH = *(const bf16x8*)&wg[(unsigned)((kc * 3 + 2) * 8 + dh * 4 + cg) << 9];
                aH[cg] = __builtin_amdgcn_mfma_f32_16x16x32_bf16(wfH, af, aH[cg], 0, 0, 0);
            }
        }
        // epilogue for this d-half
        if (valid) {
            #pragma unroll
            for (int cg = 0; cg < 4; ++cg) {
                int d0 = (dh * 4 + cg) * 16 + quad * 4;
                f32x4 h0 = *(const f32x4*)&hf[(size_t)node * 128 + d0];
                f32x4 o;
                #pragma unroll
                for (int j = 0; j < 4; ++j) {
                    float nn = tanhf_fast(aH[cg][j]);
                    o[j] = (1.f - zv[cg][j]) * nn + zv[cg][j] * h0[j];
                }
                *(f32x4*)&out[(size_t)node * 128 + d0] = o;
            }
        }
    }
}

extern "C" void kernel_launch(void* const* d_in, const int* in_sizes, int n_in,
                              void* d_out, int out_size, void* d_ws, size_t ws_size,
                              hipStream_t stream)
{
    const float* h     = (const float*)d_in[0];
    const int*   ei    = (const int*)d_in[1];
    const int*   etype = (const int*)d_in[2];
    const float* W     = (const float*)d_in[3];
    const float* b     = (const float*)d_in[4];
    const float* wih   = (const float*)d_in[5];
    const float* whh   = (const float*)d_in[6];
    const float* bih   = (const float*)d_in[7];
    const float* bhh   = (const float*)d_in[8];
    float* out = (float*)d_out;

    int E = in_sizes[1] / 2;
    int N = in_sizes[0] / HID;
    int capE = ((E + 127) / 128 + NTY) * 128;
    int nbA = (N + 255) / 256;

    char* p = (char*)d_ws;
    auto alloc = [&](size_t bytes) { char* r = p; p += (bytes + 255) & ~(size_t)255; return r; };
    unsigned short* hbf  = (unsigned short*)alloc((size_t)N * 128 * 2);
    unsigned short* wfr  = (unsigned short*)alloc((size_t)131072 * 2);
    unsigned short* wpkf = (unsigned short*)alloc((size_t)98304 * 2);
    int* tcnt    = (int*)alloc(NTY * 4);
    int* tcur    = (int*)alloc(NTY * 4);
    int* sortedT = (int*)alloc((size_t)capE * 4);
    unsigned short* M = (unsigned short*)alloc((size_t)E * 128 * 2);
    int* q     = (int*)alloc((size_t)E * 4);
    int* deg   = (int*)alloc((size_t)N * 4);
    int* start = (int*)alloc((size_t)(N + 1) * 4);
    int* dcur  = (int*)alloc((size_t)N * 4);
    int* bsum  = (int*)alloc(512 * 4);
    int mode = ((size_t)(p - (char*)d_ws) <= ws_size) ? 0 : 1;

    if (mode == 1) hipMemsetAsync(out, 0, (size_t)N * 128 * 4, stream);

    int totalConv = N * 128 + 131072 + 98304 + capE + N + NTY;
    conv_all_kernel<<<(totalConv + 255) / 256, 256, 0, stream>>>(
        h, hbf, N * 128, W, wfr, wih, whh, wpkf, sortedT, capE, deg, N, tcnt);

    hist_kernel<<<1024, 256, 0, stream>>>(etype, ei, E, tcnt, (mode == 0) ? deg : nullptr);
    if (mode == 0)
        scanA_kernel<<<nbA, 256, 0, stream>>>(deg, start, bsum, N);
    scanB_kernel<<<1, 512, 0, stream>>>(bsum, nbA, tcnt, tcur);
    if (mode == 0)
        scanC_kernel<<<nbA, 256, 0, stream>>>(start, bsum, dcur, N, E);
    scatter_agg<<<256, 256, 0, stream>>>(etype, ei, E, tcur, dcur, sortedT, q, (mode == 0) ? 1 : 0);

    msg_gemm<<<capE / 128, 256, 0, stream>>>(hbf, ei, E, etype, wfr, b, sortedT, q, M, out, mode);
    gru_fused<<<(N + 63) / 64, 256, 0, stream>>>(M, start, out, hbf, wpkf, bih, bhh, h, out, N, mode);
}

// Round 6
// 456.539 us; speedup vs baseline: 1.6118x; 1.6118x over previous
//
#include <hip/hip_runtime.h>

#define HID 128
#define NTY 8

typedef __attribute__((ext_vector_type(8))) short bf16x8;
typedef __attribute__((ext_vector_type(4))) float f32x4;

__device__ __forceinline__ unsigned short f2bf(float x) {
    unsigned u = __float_as_uint(x);
    u += 0x7FFF + ((u >> 16) & 1);          // RNE
    return (unsigned short)(u >> 16);
}
__device__ __forceinline__ float bf2f(unsigned short s) {
    return __uint_as_float(((unsigned)s) << 16);
}
__device__ __forceinline__ float sigmoidf_fast(float x) {
    return 1.f / (1.f + __expf(-x));
}
__device__ __forceinline__ float tanhf_fast(float x) {
    return 1.f - 2.f / (1.f + __expf(2.f * x));
}

// ---------------- fused prep: h->bf16, W->wfr frags, GRU->wpkf frags, memset-equivalents ----------------
// wfr[(((t*4+kc)*8+cb)*64 + lane)*8 + e] = bf16(W[t][k][d]), d=cb*16+(lane&15), k=kc*32+(lane>>4)*8+e
// wpkf[((kc*24+g3*8+ct)*64 + lane)*8 + e]: kc<4 -> wih, kc>=4 -> whh; d=ct*16+(lane&15), kk=(lane>>4)*8+e
__global__ void conv_all_kernel(const float* __restrict__ h, unsigned short* __restrict__ hbf, int nh,
                                const float* __restrict__ W, unsigned short* __restrict__ wfr,
                                const float* __restrict__ wih, const float* __restrict__ whh,
                                unsigned short* __restrict__ wpkf,
                                int* __restrict__ sortedT, int capE,
                                int* __restrict__ deg, int N, int* __restrict__ tcnt)
{
    int i = blockIdx.x * 256 + threadIdx.x;
    if (i < nh) { hbf[i] = f2bf(h[i]); return; }
    i -= nh;
    if (i < 131072) {
        int e = i & 7, lane = (i >> 3) & 63, cb = (i >> 9) & 7, kc = (i >> 12) & 3, t = i >> 14;
        int lr = lane & 15, quad = lane >> 4;
        int d = cb * 16 + lr;
        int k = kc * 32 + quad * 8 + e;
        wfr[i] = f2bf(W[(t << 14) + (k << 7) + d]);
        return;
    }
    i -= 131072;
    if (i < 98304) {
        int e = i & 7, lane = (i >> 3) & 63, f = i >> 9;   // f = kc*24+g3*8+ct
        int ct = f & 7, fg = f >> 3;                       // fg = kc*3+g3
        int g3 = fg % 3, kc = fg / 3;
        int lr = lane & 15, quad = lane >> 4;
        int d = ct * 16 + lr;
        int kk = quad * 8 + e;
        float v;
        if (kc < 4) v = wih[(g3 * 128 + d) * 128 + kc * 32 + kk];
        else        v = whh[(g3 * 128 + d) * 128 + (kc - 4) * 32 + kk];
        wpkf[i] = f2bf(v);
        return;
    }
    i -= 98304;
    if (i < capE) { sortedT[i] = -1; return; }
    i -= capE;
    if (i < N) { deg[i] = 0; return; }
    i -= N;
    if (i < NTY) tcnt[i] = 0;
}

// ---------------- sort bookkeeping (R0-proven) ----------------
__global__ void hist_kernel(const int* __restrict__ etype, const int* __restrict__ ei,
                            int E, int* __restrict__ tcnt, int* __restrict__ deg) {
    __shared__ int lc[NTY];
    if (threadIdx.x < NTY) lc[threadIdx.x] = 0;
    __syncthreads();
    int stride = gridDim.x * blockDim.x;
    for (int i = blockIdx.x * blockDim.x + threadIdx.x; i < E; i += stride) {
        atomicAdd(&lc[etype[i]], 1);
        if (deg) atomicAdd(&deg[ei[E + i]], 1);
    }
    __syncthreads();
    if (threadIdx.x < NTY) atomicAdd(&tcnt[threadIdx.x], lc[threadIdx.x]);
}

__global__ void scanA_kernel(const int* __restrict__ deg, int* __restrict__ start,
                             int* __restrict__ bsum, int N) {
    __shared__ int s[256];
    int i = blockIdx.x * 256 + threadIdx.x;
    int v = (i < N) ? deg[i] : 0;
    s[threadIdx.x] = v;
    __syncthreads();
    for (int off = 1; off < 256; off <<= 1) {
        int t = (threadIdx.x >= off) ? s[threadIdx.x - off] : 0;
        __syncthreads();
        s[threadIdx.x] += t;
        __syncthreads();
    }
    if (i < N) start[i] = s[threadIdx.x] - v;
    if (threadIdx.x == 255) bsum[blockIdx.x] = s[255];
}

// block-sum scan + fused 8-bin type scan (padded to 128)
__global__ void scanB_kernel(int* __restrict__ bsum, int nb,
                             const int* __restrict__ tcnt, int* __restrict__ tcur) {
    __shared__ int s[512];
    int tx = threadIdx.x;
    int v = (tx < nb) ? bsum[tx] : 0;
    s[tx] = v;
    __syncthreads();
    for (int off = 1; off < 512; off <<= 1) {
        int t = (tx >= off) ? s[tx - off] : 0;
        __syncthreads();
        s[tx] += t;
        __syncthreads();
    }
    if (tx < nb) bsum[tx] = s[tx] - v;
    if (tx == 0) {
        int off = 0;
        for (int t = 0; t < NTY; ++t) { tcur[t] = off; off += (tcnt[t] + 127) & ~127; }
    }
}

__global__ void scanC_kernel(int* __restrict__ start, const int* __restrict__ bsum,
                             int* __restrict__ dcur, int N, int E) {
    int i = blockIdx.x * 256 + threadIdx.x;
    if (i < N) {
        int v = start[i] + bsum[blockIdx.x];
        start[i] = v;
        dcur[i] = v;
    }
    if (i == 0) start[N] = E;
}

// block-aggregated scatter: 8 global tcur atomics per BLOCK (R0-proven)
__global__ __launch_bounds__(256) void scatter_agg(
    const int* __restrict__ etype, const int* __restrict__ ei, int E,
    int* __restrict__ tcur, int* __restrict__ dcur,
    int* __restrict__ sortedT, int* __restrict__ q, int mode)
{
    __shared__ int lcnt[NTY];
    __shared__ int lbase[NTY];
    int tx = threadIdx.x;
    int chunk = (E + gridDim.x - 1) / gridDim.x;
    int s = blockIdx.x * chunk;
    int e = s + chunk; if (e > E) e = E;
    if (tx < NTY) lcnt[tx] = 0;
    __syncthreads();
    for (int i = s + tx; i < e; i += 256)
        atomicAdd(&lcnt[etype[i]], 1);
    __syncthreads();
    if (tx < NTY) {
        lbase[tx] = atomicAdd(&tcur[tx], lcnt[tx]);
        lcnt[tx] = 0;
    }
    __syncthreads();
    for (int i = s + tx; i < e; i += 256) {
        int t = etype[i];
        int lp = atomicAdd(&lcnt[t], 1);
        sortedT[lbase[t] + lp] = i;
        if (mode) q[i] = atomicAdd(&dcur[ei[E + i]], 1);
    }
}

// ---------------- msg GEMM: 128-edge x 128-d tile, W direct from L2 (no K-loop barriers) ----------------
// Operand-swapped MFMA: D[d][e]; lane holds 4 consecutive d -> packed 8B stores.
__global__ __launch_bounds__(256) void msg_gemm(
    const unsigned short* __restrict__ hbf, const int* __restrict__ ei, int E,
    const int* __restrict__ etype, const unsigned short* __restrict__ wfr,
    const float* __restrict__ bias, const int* __restrict__ sortedT,
    const int* __restrict__ q, unsigned short* __restrict__ M,
    float* __restrict__ msum, int mode)
{
    __shared__ unsigned short hs[128][136];
    __shared__ int srcs[128], aux[128];
    __shared__ int stype;

    int tx = threadIdx.x;
    int base = blockIdx.x * 128;
    if (tx < 128) {
        int id = sortedT[base + tx];
        srcs[tx] = (id >= 0) ? ei[id] : -1;
        aux[tx]  = (id >= 0) ? (mode ? ei[E + id] : q[id]) : -1;
    }
    if (tx == 0) { int id0 = sortedT[base]; stype = (id0 >= 0) ? etype[id0] : -1; }
    __syncthreads();
    int t = stype;
    if (t < 0) return;

    for (int f = tx; f < 2048; f += 256) {
        int row = f >> 4, c8 = (f & 15) * 8;
        int s = srcs[row]; if (s < 0) s = 0;
        *(uint4*)&hs[row][c8] = *(const uint4*)&hbf[(size_t)s * 128 + c8];
    }
    __syncthreads();

    int lane = tx & 63, w = tx >> 6;
    int r0 = (w >> 1) * 64, c0 = (w & 1) * 64;   // r0: edge-tile base, c0: d-tile base
    int lr = lane & 15, quad = lane >> 4;
    f32x4 acc[4][4] = {};   // [rb(e-tile)][cb(d-tile)], D[d][e] per tile

    // W fragments lane-coalesced from L2: value-identical to R0's Bs fragments.
    const unsigned short* wt = wfr + (t << 14) + ((unsigned)(c0 >> 4) << 9) + (lane << 3);
    #pragma unroll
    for (int kc = 0; kc < 4; ++kc) {
        bf16x8 af[4], wf[4];
        #pragma unroll
        for (int rb = 0; rb < 4; ++rb) af[rb] = *(const bf16x8*)&hs[r0 + rb * 16 + lr][kc * 32 + quad * 8];
        #pragma unroll
        for (int cb = 0; cb < 4; ++cb) wf[cb] = *(const bf16x8*)&wt[(kc << 12) + (cb << 9)];
        #pragma unroll
        for (int rb = 0; rb < 4; ++rb)
            #pragma unroll
            for (int cb = 0; cb < 4; ++cb)
                acc[rb][cb] = __builtin_amdgcn_mfma_f32_16x16x32_bf16(wf[cb], af[rb], acc[rb][cb], 0, 0, 0);
    }

    // epilogue: e = r0+rb*16+lr, d = c0+cb*16+quad*4+reg (4 consecutive)
    float4 bv4[4];
    #pragma unroll
    for (int cb = 0; cb < 4; ++cb)
        bv4[cb] = *(const float4*)&bias[t * 128 + c0 + cb * 16 + quad * 4];

    #pragma unroll
    for (int rb = 0; rb < 4; ++rb) {
        int e = r0 + rb * 16 + lr;
        int mr = aux[e];
        if (mr < 0) continue;
        #pragma unroll
        for (int cb = 0; cb < 4; ++cb) {
            int d0 = c0 + cb * 16 + quad * 4;
            f32x4 a = acc[rb][cb];
            if (mode) {
                atomicAdd(&msum[(size_t)mr * 128 + d0 + 0], a[0] + bv4[cb].x);
                atomicAdd(&msum[(size_t)mr * 128 + d0 + 1], a[1] + bv4[cb].y);
                atomicAdd(&msum[(size_t)mr * 128 + d0 + 2], a[2] + bv4[cb].z);
                atomicAdd(&msum[(size_t)mr * 128 + d0 + 3], a[3] + bv4[cb].w);
            } else {
                uint2 v;
                v.x = (unsigned)f2bf(a[0] + bv4[cb].x) | ((unsigned)f2bf(a[1] + bv4[cb].y) << 16);
                v.y = (unsigned)f2bf(a[2] + bv4[cb].z) | ((unsigned)f2bf(a[3] + bv4[cb].w) << 16);
                *(uint2*)&M[(size_t)mr * 128 + d0] = v;
            }
        }
    }
}

// ---------------- fused seg-reduce + GRU: 64 nodes/block ----------------
// Stage A v3: chunked two-phase — (1) coalesced parallel copy of the block's
// CONTIGUOUS M-row span into LDS (128-row chunks), (2) per-(node,qd) serial
// reduce from LDS (short latency, no atomics, no global serial chain).
// GRU: sequential gates + d-half split (R4-identical).
__global__ __launch_bounds__(256) void gru_fused(
    const unsigned short* __restrict__ M, const int* __restrict__ start,
    const float* __restrict__ msum_fb, const unsigned short* __restrict__ hbf,
    const unsigned short* __restrict__ wpkf, const float* __restrict__ bih,
    const float* __restrict__ bhh, const float* __restrict__ hf,
    float* __restrict__ out, int N, int mode)
{
    __shared__ unsigned short chunkb[128][136];   // 128 M rows, +16B pad vs bank aliasing
    __shared__ unsigned short As[4][2048];        // per-wave 16x128 bf16 msg, XOR-swizzled
    __shared__ int bnds_l[65];

    int tx = threadIdx.x;
    int n0 = blockIdx.x * 64;

    if (tx <= 64) {
        int idx = n0 + tx; if (idx > N) idx = N;
        bnds_l[tx] = (mode == 0) ? start[idx] : 0;
    }
    __syncthreads();

    int ln = tx >> 2, qd = tx & 3;
    float a[32];
    #pragma unroll
    for (int j = 0; j < 32; ++j) a[j] = 0.f;

    if (mode == 0) {
        int rowlo = bnds_l[0], rowhi = bnds_l[64];
        int sn = bnds_l[ln], en = bnds_l[ln + 1];
        for (int cbase = rowlo; cbase < rowhi; cbase += 128) {
            int cend = cbase + 128; if (cend > rowhi) cend = rowhi;
            // phase 1: coalesced copy, 8 independent uint4 loads/thread
            #pragma unroll
            for (int it = 0; it < 8; ++it) {
                int i = tx + it * 256;
                int row = cbase + (i >> 4);
                if (row < cend)
                    *(uint4*)&chunkb[i >> 4][(i & 15) * 8] =
                        *(const uint4*)&M[(size_t)row * 128 + (i & 15) * 8];
            }
            __syncthreads();
            // phase 2: short-latency LDS serial reduce
            int lo = sn > cbase ? sn : cbase;
            int hi = en < cend ? en : cend;
            for (int r = lo; r < hi; ++r) {
                const unsigned short* mp = &chunkb[r - cbase][qd * 32];
                #pragma unroll
                for (int u = 0; u < 4; ++u) {
                    uint4 v = *(const uint4*)&mp[u * 8];
                    const unsigned short* pv = (const unsigned short*)&v;
                    #pragma unroll
                    for (int j = 0; j < 8; ++j) a[u * 8 + j] += bf2f(pv[j]);
                }
            }
            __syncthreads();
        }
    } else {
        int n = n0 + ln; int nc2 = (n < N) ? n : N - 1;
        #pragma unroll
        for (int j = 0; j < 8; ++j) {
            float4 v = *(const float4*)&msum_fb[(size_t)nc2 * 128 + qd * 32 + j * 4];
            a[j * 4 + 0] = v.x; a[j * 4 + 1] = v.y; a[j * 4 + 2] = v.z; a[j * 4 + 3] = v.w;
        }
    }

    // handoff to XOR-swizzled As (R4-identical involution)
    {
        unsigned short tmp[32];
        #pragma unroll
        for (int j = 0; j < 32; ++j) tmp[j] = f2bf(a[j]);
        int lrw = ln & 15, wv = ln >> 4;
        #pragma unroll
        for (int j = 0; j < 4; ++j) {
            int byte = (lrw << 8) + (qd << 6) + (j << 4);
            byte ^= (lrw & 7) << 4;
            *(uint4*)((char*)&As[wv][0] + byte) = *(const uint4*)&tmp[j * 8];
        }
    }
    __syncthreads();

    // ---- GRU phase (R4-identical) ----
    int lane = tx & 63, w = tx >> 6;
    int lr = lane & 15, quad = lane >> 4;
    int node = n0 + w * 16 + lr;
    bool valid = node < N;
    int nc = valid ? node : (N - 1);
    unsigned short* AsW = &As[w][0];

    bf16x8 afh[4];   // h fragments, cached
    {
        const unsigned short* hrow = hbf + ((size_t)nc << 7) + (quad << 3);
        #pragma unroll
        for (int k4 = 0; k4 < 4; ++k4) afh[k4] = *(const bf16x8*)&hrow[k4 * 32];
    }
    const unsigned short* wg = wpkf + (lane << 3);

    #pragma unroll
    for (int dh = 0; dh < 2; ++dh) {
        f32x4 aR[4] = {}, aZ[4] = {}, aH[4] = {};
        #pragma unroll
        for (int kc = 0; kc < 8; ++kc) {
            bf16x8 af;
            if (kc < 4) {
                int byte = ((lr << 8) + (kc << 6) + (quad << 4)) ^ ((lr & 7) << 4);
                af = *(const bf16x8*)((char*)AsW + byte);
            } else {
                af = afh[kc - 4];
            }
            #pragma unroll
            for (int c = 0; c < 4; ++c) {
                int ct = dh * 4 + c;
                bf16x8 wfR = *(const bf16x8*)&wg[(unsigned)((kc * 3 + 0) * 8 + ct) << 9];
                aR[c] = __builtin_amdgcn_mfma_f32_16x16x32_bf16(wfR, af, aR[c], 0, 0, 0);
                bf16x8 wfZ = *(const bf16x8*)&wg[(unsigned)((kc * 3 + 1) * 8 + ct) << 9];
                aZ[c] = __builtin_amdgcn_mfma_f32_16x16x32_bf16(wfZ, af, aZ[c], 0, 0, 0);
                if (kc >= 4) {
                    bf16x8 wfH = *(const bf16x8*)&wg[(unsigned)((kc * 3 + 2) * 8 + ct) << 9];
                    aH[c] = __builtin_amdgcn_mfma_f32_16x16x32_bf16(wfH, af, aH[c], 0, 0, 0);
                }
            }
        }
        // r, z; fold n's h-part:  aH = bin + r*(aH + bhn)
        f32x4 rv[4], zv[4];
        #pragma unroll
        for (int c = 0; c < 4; ++c) {
            int d0 = (dh * 4 + c) * 16 + quad * 4;
            f32x4 bir = *(const f32x4*)&bih[d0],       bhr = *(const f32x4*)&bhh[d0];
            f32x4 biz = *(const f32x4*)&bih[128 + d0], bhz = *(const f32x4*)&bhh[128 + d0];
            f32x4 bin = *(const f32x4*)&bih[256 + d0], bhn = *(const f32x4*)&bhh[256 + d0];
            #pragma unroll
            for (int j = 0; j < 4; ++j) {
                rv[c][j] = sigmoidf_fast(aR[c][j] + bir[j] + bhr[j]);
                zv[c][j] = sigmoidf_fast(aZ[c][j] + biz[j] + bhz[j]);
                aH[c][j] = bin[j] + rv[c][j] * (aH[c][j] + bhn[j]);
            }
        }
        // n's m-part accumulates onto folded value via MFMA C-operand
        #pragma unroll
        for (int kc = 0; kc < 4; ++kc) {
            int byte = ((lr << 8) + (kc << 6) + (quad << 4)) ^ ((lr & 7) << 4);
            bf16x8 af = *(const bf16x8*)((char*)AsW + byte);
            #pragma unroll
            for (int c = 0; c < 4; ++c) {
                bf16x8 wfH = *(const bf16x8*)&wg[(unsigned)((kc * 3 + 2) * 8 + dh * 4 + c) << 9];
                aH[c] = __builtin_amdgcn_mfma_f32_16x16x32_bf16(wfH, af, aH[c], 0, 0, 0);
            }
        }
        // epilogue for this d-half
        if (valid) {
            #pragma unroll
            for (int c = 0; c < 4; ++c) {
                int d0 = (dh * 4 + c) * 16 + quad * 4;
                f32x4 h0 = *(const f32x4*)&hf[(size_t)node * 128 + d0];
                f32x4 o;
                #pragma unroll
                for (int j = 0; j < 4; ++j) {
                    float nn = tanhf_fast(aH[c][j]);
                    o[j] = (1.f - zv[c][j]) * nn + zv[c][j] * h0[j];
                }
                *(f32x4*)&out[(size_t)node * 128 + d0] = o;
            }
        }
    }
}

extern "C" void kernel_launch(void* const* d_in, const int* in_sizes, int n_in,
                              void* d_out, int out_size, void* d_ws, size_t ws_size,
                              hipStream_t stream)
{
    const float* h     = (const float*)d_in[0];
    const int*   ei    = (const int*)d_in[1];
    const int*   etype = (const int*)d_in[2];
    const float* W     = (const float*)d_in[3];
    const float* b     = (const float*)d_in[4];
    const float* wih   = (const float*)d_in[5];
    const float* whh   = (const float*)d_in[6];
    const float* bih   = (const float*)d_in[7];
    const float* bhh   = (const float*)d_in[8];
    float* out = (float*)d_out;

    int E = in_sizes[1] / 2;
    int N = in_sizes[0] / HID;
    int capE = ((E + 127) / 128 + NTY) * 128;
    int nbA = (N + 255) / 256;

    char* p = (char*)d_ws;
    auto alloc = [&](size_t bytes) { char* r = p; p += (bytes + 255) & ~(size_t)255; return r; };
    unsigned short* hbf  = (unsigned short*)alloc((size_t)N * 128 * 2);
    unsigned short* wfr  = (unsigned short*)alloc((size_t)131072 * 2);
    unsigned short* wpkf = (unsigned short*)alloc((size_t)98304 * 2);
    int* tcnt    = (int*)alloc(NTY * 4);
    int* tcur    = (int*)alloc(NTY * 4);
    int* sortedT = (int*)alloc((size_t)capE * 4);
    unsigned short* M = (unsigned short*)alloc((size_t)E * 128 * 2);
    int* q     = (int*)alloc((size_t)E * 4);
    int* deg   = (int*)alloc((size_t)N * 4);
    int* start = (int*)alloc((size_t)(N + 1) * 4);
    int* dcur  = (int*)alloc((size_t)N * 4);
    int* bsum  = (int*)alloc(512 * 4);
    int mode = ((size_t)(p - (char*)d_ws) <= ws_size) ? 0 : 1;

    if (mode == 1) hipMemsetAsync(out, 0, (size_t)N * 128 * 4, stream);

    int totalConv = N * 128 + 131072 + 98304 + capE + N + NTY;
    conv_all_kernel<<<(totalConv + 255) / 256, 256, 0, stream>>>(
        h, hbf, N * 128, W, wfr, wih, whh, wpkf, sortedT, capE, deg, N, tcnt);

    hist_kernel<<<1024, 256, 0, stream>>>(etype, ei, E, tcnt, (mode == 0) ? deg : nullptr);
    if (mode == 0)
        scanA_kernel<<<nbA, 256, 0, stream>>>(deg, start, bsum, N);
    scanB_kernel<<<1, 512, 0, stream>>>(bsum, nbA, tcnt, tcur);
    if (mode == 0)
        scanC_kernel<<<nbA, 256, 0, stream>>>(start, bsum, dcur, N, E);
    scatter_agg<<<256, 256, 0, stream>>>(etype, ei, E, tcur, dcur, sortedT, q, (mode == 0) ? 1 : 0);

    msg_gemm<<<capE / 128, 256, 0, stream>>>(hbf, ei, E, etype, wfr, b, sortedT, q, M, out, mode);
    gru_fused<<<(N + 63) / 64, 256, 0, stream>>>(M, start, out, hbf, wpkf, bih, bhh, h, out, N, mode);
}

// Round 7
// 384.988 us; speedup vs baseline: 1.9113x; 1.1859x over previous
//
#include <hip/hip_runtime.h>

#define HID 128
#define NTY 8

typedef __attribute__((ext_vector_type(8))) short bf16x8;
typedef __attribute__((ext_vector_type(4))) float f32x4;

__device__ __forceinline__ unsigned short f2bf(float x) {
    unsigned u = __float_as_uint(x);
    u += 0x7FFF + ((u >> 16) & 1);          // RNE
    return (unsigned short)(u >> 16);
}
__device__ __forceinline__ float bf2f(unsigned short s) {
    return __uint_as_float(((unsigned)s) << 16);
}
__device__ __forceinline__ float sigmoidf_fast(float x) {
    return 1.f / (1.f + __expf(-x));
}
__device__ __forceinline__ float tanhf_fast(float x) {
    return 1.f - 2.f / (1.f + __expf(2.f * x));
}

// ---------------- fused prep: h->bf16, W->wfr frags, GRU->wpkf frags, memset-equivalents ----------------
// wfr[(((t*4+kc)*8+cb)*64 + lane)*8 + e] = bf16(W[t][k][d]), d=cb*16+(lane&15), k=kc*32+(lane>>4)*8+e
// wpkf[((kc*24+g3*8+ct)*64 + lane)*8 + e]: kc<4 -> wih, kc>=4 -> whh; d=ct*16+(lane&15), kk=(lane>>4)*8+e
__global__ void conv_all_kernel(const float* __restrict__ h, unsigned short* __restrict__ hbf, int nh,
                                const float* __restrict__ W, unsigned short* __restrict__ wfr,
                                const float* __restrict__ wih, const float* __restrict__ whh,
                                unsigned short* __restrict__ wpkf,
                                int* __restrict__ sortedT, int capE,
                                int* __restrict__ deg, int N, int* __restrict__ tcnt)
{
    int i = blockIdx.x * 256 + threadIdx.x;
    if (i < nh) { hbf[i] = f2bf(h[i]); return; }
    i -= nh;
    if (i < 131072) {
        int e = i & 7, lane = (i >> 3) & 63, cb = (i >> 9) & 7, kc = (i >> 12) & 3, t = i >> 14;
        int lr = lane & 15, quad = lane >> 4;
        int d = cb * 16 + lr;
        int k = kc * 32 + quad * 8 + e;
        wfr[i] = f2bf(W[(t << 14) + (k << 7) + d]);
        return;
    }
    i -= 131072;
    if (i < 98304) {
        int e = i & 7, lane = (i >> 3) & 63, f = i >> 9;   // f = kc*24+g3*8+ct
        int ct = f & 7, fg = f >> 3;                       // fg = kc*3+g3
        int g3 = fg % 3, kc = fg / 3;
        int lr = lane & 15, quad = lane >> 4;
        int d = ct * 16 + lr;
        int kk = quad * 8 + e;
        float v;
        if (kc < 4) v = wih[(g3 * 128 + d) * 128 + kc * 32 + kk];
        else        v = whh[(g3 * 128 + d) * 128 + (kc - 4) * 32 + kk];
        wpkf[i] = f2bf(v);
        return;
    }
    i -= 98304;
    if (i < capE) { sortedT[i] = -1; return; }
    i -= capE;
    if (i < N) { deg[i] = 0; return; }
    i -= N;
    if (i < NTY) tcnt[i] = 0;
}

// ---------------- sort bookkeeping (R0-proven) ----------------
__global__ void hist_kernel(const int* __restrict__ etype, const int* __restrict__ ei,
                            int E, int* __restrict__ tcnt, int* __restrict__ deg) {
    __shared__ int lc[NTY];
    if (threadIdx.x < NTY) lc[threadIdx.x] = 0;
    __syncthreads();
    int stride = gridDim.x * blockDim.x;
    for (int i = blockIdx.x * blockDim.x + threadIdx.x; i < E; i += stride) {
        atomicAdd(&lc[etype[i]], 1);
        if (deg) atomicAdd(&deg[ei[E + i]], 1);
    }
    __syncthreads();
    if (threadIdx.x < NTY) atomicAdd(&tcnt[threadIdx.x], lc[threadIdx.x]);
}

__global__ void scanA_kernel(const int* __restrict__ deg, int* __restrict__ start,
                             int* __restrict__ bsum, int N) {
    __shared__ int s[256];
    int i = blockIdx.x * 256 + threadIdx.x;
    int v = (i < N) ? deg[i] : 0;
    s[threadIdx.x] = v;
    __syncthreads();
    for (int off = 1; off < 256; off <<= 1) {
        int t = (threadIdx.x >= off) ? s[threadIdx.x - off] : 0;
        __syncthreads();
        s[threadIdx.x] += t;
        __syncthreads();
    }
    if (i < N) start[i] = s[threadIdx.x] - v;
    if (threadIdx.x == 255) bsum[blockIdx.x] = s[255];
}

// block-sum scan + fused 8-bin type scan (padded to 128)
__global__ void scanB_kernel(int* __restrict__ bsum, int nb,
                             const int* __restrict__ tcnt, int* __restrict__ tcur) {
    __shared__ int s[512];
    int tx = threadIdx.x;
    int v = (tx < nb) ? bsum[tx] : 0;
    s[tx] = v;
    __syncthreads();
    for (int off = 1; off < 512; off <<= 1) {
        int t = (tx >= off) ? s[tx - off] : 0;
        __syncthreads();
        s[tx] += t;
        __syncthreads();
    }
    if (tx < nb) bsum[tx] = s[tx] - v;
    if (tx == 0) {
        int off = 0;
        for (int t = 0; t < NTY; ++t) { tcur[t] = off; off += (tcnt[t] + 127) & ~127; }
    }
}

__global__ void scanC_kernel(int* __restrict__ start, const int* __restrict__ bsum,
                             int* __restrict__ dcur, int N, int E) {
    int i = blockIdx.x * 256 + threadIdx.x;
    if (i < N) {
        int v = start[i] + bsum[blockIdx.x];
        start[i] = v;
        dcur[i] = v;
    }
    if (i == 0) start[N] = E;
}

// block-aggregated scatter: 8 global tcur atomics per BLOCK (R0-proven)
__global__ __launch_bounds__(256) void scatter_agg(
    const int* __restrict__ etype, const int* __restrict__ ei, int E,
    int* __restrict__ tcur, int* __restrict__ dcur,
    int* __restrict__ sortedT, int* __restrict__ q, int mode)
{
    __shared__ int lcnt[NTY];
    __shared__ int lbase[NTY];
    int tx = threadIdx.x;
    int chunk = (E + gridDim.x - 1) / gridDim.x;
    int s = blockIdx.x * chunk;
    int e = s + chunk; if (e > E) e = E;
    if (tx < NTY) lcnt[tx] = 0;
    __syncthreads();
    for (int i = s + tx; i < e; i += 256)
        atomicAdd(&lcnt[etype[i]], 1);
    __syncthreads();
    if (tx < NTY) {
        lbase[tx] = atomicAdd(&tcur[tx], lcnt[tx]);
        lcnt[tx] = 0;
    }
    __syncthreads();
    for (int i = s + tx; i < e; i += 256) {
        int t = etype[i];
        int lp = atomicAdd(&lcnt[t], 1);
        sortedT[lbase[t] + lp] = i;
        if (mode) q[i] = atomicAdd(&dcur[ei[E + i]], 1);
    }
}

// ---------------- msg GEMM: 128-edge x 128-d tile, W direct from L2 (no K-loop barriers) ----------------
// Operand-swapped MFMA: D[d][e]; lane holds 4 consecutive d -> packed 8B stores.
__global__ __launch_bounds__(256) void msg_gemm(
    const unsigned short* __restrict__ hbf, const int* __restrict__ ei, int E,
    const int* __restrict__ etype, const unsigned short* __restrict__ wfr,
    const float* __restrict__ bias, const int* __restrict__ sortedT,
    const int* __restrict__ q, unsigned short* __restrict__ M,
    float* __restrict__ msum, int mode)
{
    __shared__ unsigned short hs[128][136];
    __shared__ int srcs[128], aux[128];
    __shared__ int stype;

    int tx = threadIdx.x;
    int base = blockIdx.x * 128;
    if (tx < 128) {
        int id = sortedT[base + tx];
        srcs[tx] = (id >= 0) ? ei[id] : -1;
        aux[tx]  = (id >= 0) ? (mode ? ei[E + id] : q[id]) : -1;
    }
    if (tx == 0) { int id0 = sortedT[base]; stype = (id0 >= 0) ? etype[id0] : -1; }
    __syncthreads();
    int t = stype;
    if (t < 0) return;

    for (int f = tx; f < 2048; f += 256) {
        int row = f >> 4, c8 = (f & 15) * 8;
        int s = srcs[row]; if (s < 0) s = 0;
        *(uint4*)&hs[row][c8] = *(const uint4*)&hbf[(size_t)s * 128 + c8];
    }
    __syncthreads();

    int lane = tx & 63, w = tx >> 6;
    int r0 = (w >> 1) * 64, c0 = (w & 1) * 64;   // r0: edge-tile base, c0: d-tile base
    int lr = lane & 15, quad = lane >> 4;
    f32x4 acc[4][4] = {};   // [rb(e-tile)][cb(d-tile)], D[d][e] per tile

    // W fragments lane-coalesced from L2.
    const unsigned short* wt = wfr + (t << 14) + ((unsigned)(c0 >> 4) << 9) + (lane << 3);
    #pragma unroll
    for (int kc = 0; kc < 4; ++kc) {
        bf16x8 af[4], wf[4];
        #pragma unroll
        for (int rb = 0; rb < 4; ++rb) af[rb] = *(const bf16x8*)&hs[r0 + rb * 16 + lr][kc * 32 + quad * 8];
        #pragma unroll
        for (int cb = 0; cb < 4; ++cb) wf[cb] = *(const bf16x8*)&wt[(kc << 12) + (cb << 9)];
        #pragma unroll
        for (int rb = 0; rb < 4; ++rb)
            #pragma unroll
            for (int cb = 0; cb < 4; ++cb)
                acc[rb][cb] = __builtin_amdgcn_mfma_f32_16x16x32_bf16(wf[cb], af[rb], acc[rb][cb], 0, 0, 0);
    }

    // epilogue: e = r0+rb*16+lr, d = c0+cb*16+quad*4+reg (4 consecutive)
    float4 bv4[4];
    #pragma unroll
    for (int cb = 0; cb < 4; ++cb)
        bv4[cb] = *(const float4*)&bias[t * 128 + c0 + cb * 16 + quad * 4];

    #pragma unroll
    for (int rb = 0; rb < 4; ++rb) {
        int e = r0 + rb * 16 + lr;
        int mr = aux[e];
        if (mr < 0) continue;
        #pragma unroll
        for (int cb = 0; cb < 4; ++cb) {
            int d0 = c0 + cb * 16 + quad * 4;
            f32x4 a = acc[rb][cb];
            if (mode) {
                atomicAdd(&msum[(size_t)mr * 128 + d0 + 0], a[0] + bv4[cb].x);
                atomicAdd(&msum[(size_t)mr * 128 + d0 + 1], a[1] + bv4[cb].y);
                atomicAdd(&msum[(size_t)mr * 128 + d0 + 2], a[2] + bv4[cb].z);
                atomicAdd(&msum[(size_t)mr * 128 + d0 + 3], a[3] + bv4[cb].w);
            } else {
                uint2 v;
                v.x = (unsigned)f2bf(a[0] + bv4[cb].x) | ((unsigned)f2bf(a[1] + bv4[cb].y) << 16);
                v.y = (unsigned)f2bf(a[2] + bv4[cb].z) | ((unsigned)f2bf(a[3] + bv4[cb].w) << 16);
                *(uint2*)&M[(size_t)mr * 128 + d0] = v;
            }
        }
    }
}

// ---------------- fused seg-reduce + GRU: 64 nodes/block, 512 threads ----------------
// Stage A: 8 threads/node (32B each), serial row walk + 1-deep prefetch (R0-proven pattern,
// chain instrs halved vs 4-thread version). GRU: single-pass parallel gates (each weight
// fragment loaded ONCE — R0's 121us structure), 8 waves of 16 nodes x 64 d -> 64 f32 acc.
__global__ __launch_bounds__(512, 4) void gru_fused(
    const unsigned short* __restrict__ M, const int* __restrict__ start,
    const float* __restrict__ msum_fb, const unsigned short* __restrict__ hbf,
    const unsigned short* __restrict__ wpkf, const float* __restrict__ bih,
    const float* __restrict__ bhh, const float* __restrict__ hf,
    float* __restrict__ out, int N, int mode)
{
    __shared__ unsigned short As[4][2048];   // group g: 16 nodes x 128 bf16 msg, XOR-swizzled
    __shared__ int bnds_l[65];

    int tx = threadIdx.x;
    int n0 = blockIdx.x * 64;

    if (tx <= 64) {
        int idx = n0 + tx; if (idx > N) idx = N;
        bnds_l[tx] = (mode == 0) ? start[idx] : 0;
    }

    int lane = tx & 63, w = tx >> 6;
    int lr = lane & 15, quad = lane >> 4;
    int rt = w & 3, cg = w >> 2;            // wave owns nodes rt*16.., d-cols cg*64..
    int node = n0 + rt * 16 + lr;
    bool valid = node < N;
    int nc = valid ? node : (N - 1);

    // prefetch h fragments early: 4 independent global loads in flight under stage A
    bf16x8 afh[4];
    {
        const unsigned short* hrow = hbf + ((size_t)nc << 7) + (quad << 3);
        #pragma unroll
        for (int k4 = 0; k4 < 4; ++k4) afh[k4] = *(const bf16x8*)&hrow[k4 * 32];
    }
    __syncthreads();   // bnds ready

    // ---- stage A: thread (ln, j8) reduces shorts [j8*16, j8*16+16) of its node's rows ----
    {
        int ln = tx >> 3, j8 = tx & 7;
        float a[16];
        #pragma unroll
        for (int j = 0; j < 16; ++j) a[j] = 0.f;

        if (mode == 0) {
            int rs = bnds_l[ln], re = bnds_l[ln + 1];
            uint4 c0v, c1v;
            if (rs < re) {
                const unsigned short* p = M + (size_t)rs * 128 + j8 * 16;
                c0v = *(const uint4*)p;
                c1v = *(const uint4*)(p + 8);
            }
            for (int r = rs; r < re; ++r) {
                uint4 p0 = c0v, p1 = c1v;
                if (r + 1 < re) {
                    const unsigned short* pn = M + (size_t)(r + 1) * 128 + j8 * 16;
                    c0v = *(const uint4*)pn;
                    c1v = *(const uint4*)(pn + 8);
                }
                const unsigned short* q0 = (const unsigned short*)&p0;
                const unsigned short* q1 = (const unsigned short*)&p1;
                #pragma unroll
                for (int u = 0; u < 8; ++u) {
                    a[u]     += bf2f(q0[u]);
                    a[8 + u] += bf2f(q1[u]);
                }
            }
        } else {
            int n = n0 + ln; int nc2 = (n < N) ? n : N - 1;
            #pragma unroll
            for (int j = 0; j < 4; ++j) {
                float4 v = *(const float4*)&msum_fb[(size_t)nc2 * 128 + j8 * 16 + j * 4];
                a[j * 4 + 0] = v.x; a[j * 4 + 1] = v.y; a[j * 4 + 2] = v.z; a[j * 4 + 3] = v.w;
            }
        }

        unsigned short tmp[16];
        #pragma unroll
        for (int j = 0; j < 16; ++j) tmp[j] = f2bf(a[j]);
        int lrw = ln & 15, wv = ln >> 4;
        int swz = (lrw & 7) << 4;
        int b0 = ((lrw << 8) + (j8 << 5)) ^ swz;
        int b1 = ((lrw << 8) + (j8 << 5) + 16) ^ swz;
        *(uint4*)((char*)&As[wv][0] + b0) = *(const uint4*)&tmp[0];
        *(uint4*)((char*)&As[wv][0] + b1) = *(const uint4*)&tmp[8];
    }
    __syncthreads();

    // ---- GRU: single-pass parallel gates; 96 weight loads + 96 MFMAs per wave ----
    const unsigned short* AsW = &As[rt][0];
    const unsigned short* wg = wpkf + (lane << 3);

    f32x4 aR[4] = {}, aZ[4] = {}, aI[4] = {}, aH[4] = {};
    #pragma unroll
    for (int kc = 0; kc < 8; ++kc) {
        bf16x8 af;
        if (kc < 4) {
            int byte = ((lr << 8) + (kc << 6) + (quad << 4)) ^ ((lr & 7) << 4);
            af = *(const bf16x8*)((char*)AsW + byte);
        } else {
            af = afh[kc - 4];
        }
        #pragma unroll
        for (int g3 = 0; g3 < 3; ++g3) {
            #pragma unroll
            for (int ct = 0; ct < 4; ++ct) {
                bf16x8 wf = *(const bf16x8*)&wg[(unsigned)((kc * 3 + g3) * 8 + cg * 4 + ct) << 9];
                if (g3 == 0)      aR[ct] = __builtin_amdgcn_mfma_f32_16x16x32_bf16(wf, af, aR[ct], 0, 0, 0);
                else if (g3 == 1) aZ[ct] = __builtin_amdgcn_mfma_f32_16x16x32_bf16(wf, af, aZ[ct], 0, 0, 0);
                else if (kc < 4)  aI[ct] = __builtin_amdgcn_mfma_f32_16x16x32_bf16(wf, af, aI[ct], 0, 0, 0);
                else              aH[ct] = __builtin_amdgcn_mfma_f32_16x16x32_bf16(wf, af, aH[ct], 0, 0, 0);
            }
        }
    }

    // ---- epilogue: node = col (lr), d = cg*64 + ct*16 + quad*4 + reg ----
    if (valid) {
        #pragma unroll
        for (int ct = 0; ct < 4; ++ct) {
            int d0 = cg * 64 + ct * 16 + quad * 4;
            f32x4 bir = *(const f32x4*)&bih[d0],       bhr = *(const f32x4*)&bhh[d0];
            f32x4 biz = *(const f32x4*)&bih[128 + d0], bhz = *(const f32x4*)&bhh[128 + d0];
            f32x4 bin = *(const f32x4*)&bih[256 + d0], bhn = *(const f32x4*)&bhh[256 + d0];
            f32x4 h0 = *(const f32x4*)&hf[(size_t)node * 128 + d0];
            f32x4 o;
            #pragma unroll
            for (int j = 0; j < 4; ++j) {
                float r  = sigmoidf_fast(aR[ct][j] + bir[j] + bhr[j]);
                float z  = sigmoidf_fast(aZ[ct][j] + biz[j] + bhz[j]);
                float nn = tanhf_fast(aI[ct][j] + bin[j] + r * (aH[ct][j] + bhn[j]));
                o[j] = (1.f - z) * nn + z * h0[j];
            }
            *(f32x4*)&out[(size_t)node * 128 + d0] = o;
        }
    }
}

extern "C" void kernel_launch(void* const* d_in, const int* in_sizes, int n_in,
                              void* d_out, int out_size, void* d_ws, size_t ws_size,
                              hipStream_t stream)
{
    const float* h     = (const float*)d_in[0];
    const int*   ei    = (const int*)d_in[1];
    const int*   etype = (const int*)d_in[2];
    const float* W     = (const float*)d_in[3];
    const float* b     = (const float*)d_in[4];
    const float* wih   = (const float*)d_in[5];
    const float* whh   = (const float*)d_in[6];
    const float* bih   = (const float*)d_in[7];
    const float* bhh   = (const float*)d_in[8];
    float* out = (float*)d_out;

    int E = in_sizes[1] / 2;
    int N = in_sizes[0] / HID;
    int capE = ((E + 127) / 128 + NTY) * 128;
    int nbA = (N + 255) / 256;

    char* p = (char*)d_ws;
    auto alloc = [&](size_t bytes) { char* r = p; p += (bytes + 255) & ~(size_t)255; return r; };
    unsigned short* hbf  = (unsigned short*)alloc((size_t)N * 128 * 2);
    unsigned short* wfr  = (unsigned short*)alloc((size_t)131072 * 2);
    unsigned short* wpkf = (unsigned short*)alloc((size_t)98304 * 2);
    int* tcnt    = (int*)alloc(NTY * 4);
    int* tcur    = (int*)alloc(NTY * 4);
    int* sortedT = (int*)alloc((size_t)capE * 4);
    unsigned short* M = (unsigned short*)alloc((size_t)E * 128 * 2);
    int* q     = (int*)alloc((size_t)E * 4);
    int* deg   = (int*)alloc((size_t)N * 4);
    int* start = (int*)alloc((size_t)(N + 1) * 4);
    int* dcur  = (int*)alloc((size_t)N * 4);
    int* bsum  = (int*)alloc(512 * 4);
    int mode = ((size_t)(p - (char*)d_ws) <= ws_size) ? 0 : 1;

    if (mode == 1) hipMemsetAsync(out, 0, (size_t)N * 128 * 4, stream);

    int totalConv = N * 128 + 131072 + 98304 + capE + N + NTY;
    conv_all_kernel<<<(totalConv + 255) / 256, 256, 0, stream>>>(
        h, hbf, N * 128, W, wfr, wih, whh, wpkf, sortedT, capE, deg, N, tcnt);

    hist_kernel<<<1024, 256, 0, stream>>>(etype, ei, E, tcnt, (mode == 0) ? deg : nullptr);
    if (mode == 0)
        scanA_kernel<<<nbA, 256, 0, stream>>>(deg, start, bsum, N);
    scanB_kernel<<<1, 512, 0, stream>>>(bsum, nbA, tcnt, tcur);
    if (mode == 0)
        scanC_kernel<<<nbA, 256, 0, stream>>>(start, bsum, dcur, N, E);
    scatter_agg<<<256, 256, 0, stream>>>(etype, ei, E, tcur, dcur, sortedT, q, (mode == 0) ? 1 : 0);

    msg_gemm<<<capE / 128, 256, 0, stream>>>(hbf, ei, E, etype, wfr, b, sortedT, q, M, out, mode);
    gru_fused<<<(N + 63) / 64, 512, 0, stream>>>(M, start, out, hbf, wpkf, bih, bhh, h, out, N, mode);
}